// Round 6
// baseline (65.631 us; speedup 1.0000x reference)
//
#include <hip/hip_runtime.h>
#include <cmath>

// SE block: windowed mean-pool -> softsign(mW1+b1) -> sigmoid(softsign(hW2+b2)) -> gate x.
// B=32, M=2048, D=512, H=64, WIN=16 (M % WIN == 0, so reference edge-pad is a no-op).
// R5: occupancy attack. The compiler was already rematerializing the "x in registers"
//     loads (R4 VGPR=60 < 64 needed), so phase 4 re-reads x regardless — make that
//     explicit, and spend the budget on resident blocks instead:
//     - mean folded into matmul1 (one less barrier, no s_m4)
//     - LDS phase-aliased 33.3 KB -> ~17 KB  => 8 blocks/CU (was 4)
//     - NW=2 windows/block amortizes weight L2 traffic (512 MB aggregate)
//     8 blocks/CU in different phases overlap HBM latency with FMA phases.

constexpr int WIN = 16;
constexpr int D   = 512;
constexpr int H   = 64;
constexpr int TPB = 256;
constexpr int NW  = 2;                 // windows per block

__global__ __launch_bounds__(TPB) void se_block_kernel(
    const float* __restrict__ x,
    const float* __restrict__ W1,
    const float* __restrict__ b1,
    const float* __restrict__ W2,
    const float* __restrict__ b2,
    float* __restrict__ y)
{
    const int tid = threadIdx.x;
    // Block handles NW consecutive windows: contiguous NW*WIN*D floats.
    const size_t base = (size_t)blockIdx.x * (size_t)(NW * WIN * D);
    const float4* __restrict__ xw = reinterpret_cast<const float4*>(x + base);
    float4*       __restrict__ yw = reinterpret_cast<float4*>(y + base);

    const float4* __restrict__ W1f4 = reinterpret_cast<const float4*>(W1); // [512] rows x 16 f4
    const float4* __restrict__ W2f4 = reinterpret_cast<const float4*>(W2); // [64] rows x 128 f4
    const float4* __restrict__ b2f4 = reinterpret_cast<const float4*>(b2);

    // ---- Phase-aliased LDS (~17 KB total => 8 blocks/CU) ----
    // region A (8 KB): s_ps [NW][256] f4   (ph1 -> ph2)
    //                  s_gp [2][NW][128] f4 (ph3 -> ph3b)   [aliased, disjoint lifetime]
    // region B (8 KB): s_hp [16][NW][16] f4 (ph2 -> ph2b)
    //                  s_g4 [NW][128] f4    (ph3b -> ph4)   [aliased, disjoint lifetime]
    // region C (0.5 KB): s_h [NW][64] float
    __shared__ __align__(16) char s_regionA[NW * TPB * 16];
    __shared__ __align__(16) char s_regionB[16 * NW * 16 * 16];
    __shared__ float s_h[NW][H];

    float4* s_ps = reinterpret_cast<float4*>(s_regionA);       // [NW][256]
    float4* s_gp = reinterpret_cast<float4*>(s_regionA);       // [2][NW][128]
    float4* s_hp = reinterpret_cast<float4*>(s_regionB);       // [16][NW][16]
    float4* s_g4 = reinterpret_cast<float4*>(s_regionB);       // [NW][128]

    // ================= Phase 1: per-thread partial sums of x =================
    // Window w, float4 element e = i*256+tid: col c = tid&127 (fixed per thread),
    // rows covered = {2i + (tid>>7)} i=0..7  -> partner pair (tid, tid+128).
#pragma unroll
    for (int w = 0; w < NW; ++w) {
        float4 ps = make_float4(0.f, 0.f, 0.f, 0.f);
#pragma unroll
        for (int i = 0; i < 8; ++i) {
            const float4 v = xw[w * 2048 + i * TPB + tid];
            ps.x += v.x; ps.y += v.y; ps.z += v.z; ps.w += v.w;
        }
        s_ps[w * TPB + tid] = ps;
    }
    __syncthreads();

    // ================= Phase 2: matmul1 with mean folded in =================
    // h_pre[j] = (1/16) * sum_k (ps[k] + ps_pair[k]) * W1[k][j].
    // Thread = (p = tid>>4 k-part, j4 = tid&15). k in [p*32, p*32+32).
    {
        const int p  = tid >> 4;
        const int j4 = tid & 15;
        float4 acc[NW];
#pragma unroll
        for (int w = 0; w < NW; ++w) acc[w] = make_float4(0.f, 0.f, 0.f, 0.f);
#pragma unroll 2
        for (int kk4 = 0; kk4 < 8; ++kk4) {
            const int c4 = p * 8 + kk4;                 // float4 group of k
            const int k  = c4 * 4;
            const float4 w0 = W1f4[(size_t)(k + 0) * 16 + j4];
            const float4 w1 = W1f4[(size_t)(k + 1) * 16 + j4];
            const float4 w2 = W1f4[(size_t)(k + 2) * 16 + j4];
            const float4 w3 = W1f4[(size_t)(k + 3) * 16 + j4];
#pragma unroll
            for (int w = 0; w < NW; ++w) {
                const float4 a = s_ps[w * TPB + c4];
                const float4 b = s_ps[w * TPB + c4 + 128];
                const float mv0 = a.x + b.x, mv1 = a.y + b.y;
                const float mv2 = a.z + b.z, mv3 = a.w + b.w;
                acc[w].x = fmaf(mv0, w0.x, acc[w].x); acc[w].y = fmaf(mv0, w0.y, acc[w].y);
                acc[w].z = fmaf(mv0, w0.z, acc[w].z); acc[w].w = fmaf(mv0, w0.w, acc[w].w);
                acc[w].x = fmaf(mv1, w1.x, acc[w].x); acc[w].y = fmaf(mv1, w1.y, acc[w].y);
                acc[w].z = fmaf(mv1, w1.z, acc[w].z); acc[w].w = fmaf(mv1, w1.w, acc[w].w);
                acc[w].x = fmaf(mv2, w2.x, acc[w].x); acc[w].y = fmaf(mv2, w2.y, acc[w].y);
                acc[w].z = fmaf(mv2, w2.z, acc[w].z); acc[w].w = fmaf(mv2, w2.w, acc[w].w);
                acc[w].x = fmaf(mv3, w3.x, acc[w].x); acc[w].y = fmaf(mv3, w3.y, acc[w].y);
                acc[w].z = fmaf(mv3, w3.z, acc[w].z); acc[w].w = fmaf(mv3, w3.w, acc[w].w);
            }
        }
        __syncthreads();   // s_ps reads done before s_hp writes land in region B (disjoint), but
                           // needed anyway before ph2b reads s_hp -- keep single barrier here.
        const float sc = 1.0f / 16.0f;  // deferred mean scale
#pragma unroll
        for (int w = 0; w < NW; ++w) {
            float4 v = acc[w];
            v.x *= sc; v.y *= sc; v.z *= sc; v.w *= sc;
            s_hp[(p * NW + w) * 16 + j4] = v;
        }
    }
    __syncthreads();

    // ================= Phase 2b: reduce 16 k-parts, +b1, softsign =================
    if (tid < NW * H) {
        const float* s_hpf = reinterpret_cast<const float*>(s_hp);
        const int w = tid >> 6;
        const int j = tid & 63;
        float s = b1[j];
#pragma unroll
        for (int p = 0; p < 16; ++p) s += s_hpf[(p * NW + w) * H + j];
        s_h[w][j] = s / (1.0f + fabsf(s));
    }
    __syncthreads();

    // ================= Phase 3: matmul2, 2-way j-split =================
    // Thread = (q = tid>>7 j-part, d4 = tid&127). j in [q*32, q*32+32).
    {
        const float4* s_h4 = reinterpret_cast<const float4*>(&s_h[0][0]); // [NW][16]
        const int q  = tid >> 7;
        const int d4 = tid & 127;
        float4 acc[NW];
#pragma unroll
        for (int w = 0; w < NW; ++w) acc[w] = make_float4(0.f, 0.f, 0.f, 0.f);
#pragma unroll 2
        for (int jj4 = 0; jj4 < 8; ++jj4) {
            const int jg = q * 8 + jj4;                 // float4 group of j
            const int j  = jg * 4;
            const float4 w0 = W2f4[(size_t)(j + 0) * 128 + d4];
            const float4 w1 = W2f4[(size_t)(j + 1) * 128 + d4];
            const float4 w2 = W2f4[(size_t)(j + 2) * 128 + d4];
            const float4 w3 = W2f4[(size_t)(j + 3) * 128 + d4];
#pragma unroll
            for (int w = 0; w < NW; ++w) {
                const float4 hv = s_h4[w * 16 + jg];
                acc[w].x = fmaf(hv.x, w0.x, acc[w].x); acc[w].y = fmaf(hv.x, w0.y, acc[w].y);
                acc[w].z = fmaf(hv.x, w0.z, acc[w].z); acc[w].w = fmaf(hv.x, w0.w, acc[w].w);
                acc[w].x = fmaf(hv.y, w1.x, acc[w].x); acc[w].y = fmaf(hv.y, w1.y, acc[w].y);
                acc[w].z = fmaf(hv.y, w1.z, acc[w].z); acc[w].w = fmaf(hv.y, w1.w, acc[w].w);
                acc[w].x = fmaf(hv.z, w2.x, acc[w].x); acc[w].y = fmaf(hv.z, w2.y, acc[w].y);
                acc[w].z = fmaf(hv.z, w2.z, acc[w].z); acc[w].w = fmaf(hv.z, w2.w, acc[w].w);
                acc[w].x = fmaf(hv.w, w3.x, acc[w].x); acc[w].y = fmaf(hv.w, w3.y, acc[w].y);
                acc[w].z = fmaf(hv.w, w3.z, acc[w].z); acc[w].w = fmaf(hv.w, w3.w, acc[w].w);
            }
        }
        __syncthreads();   // s_ps (region A) fully dead; safe to overwrite as s_gp
#pragma unroll
        for (int w = 0; w < NW; ++w) s_gp[(q * NW + w) * 128 + d4] = acc[w];
    }
    __syncthreads();

    // ================= Phase 3b: reduce 2 j-parts, +b2, softsign, sigmoid =================
    {
        const int w  = tid >> 7;
        const int d4 = tid & 127;
        const float4 a  = s_gp[(0 * NW + w) * 128 + d4];
        const float4 b  = s_gp[(1 * NW + w) * 128 + d4];
        const float4 bb = b2f4[d4];
        float4 s;
        s.x = a.x + b.x + bb.x; s.y = a.y + b.y + bb.y;
        s.z = a.z + b.z + bb.z; s.w = a.w + b.w + bb.w;
        s.x = s.x / (1.0f + fabsf(s.x)); s.y = s.y / (1.0f + fabsf(s.y));
        s.z = s.z / (1.0f + fabsf(s.z)); s.w = s.w / (1.0f + fabsf(s.w));
        float4 g;
        g.x = 1.0f / (1.0f + __expf(-s.x)); g.y = 1.0f / (1.0f + __expf(-s.y));
        g.z = 1.0f / (1.0f + __expf(-s.z)); g.w = 1.0f / (1.0f + __expf(-s.w));
        __syncthreads();   // s_hp (region B) reads done in ph2b; safe to overwrite as s_g4
        s_g4[w * 128 + d4] = g;
    }
    __syncthreads();

    // ================= Phase 4: re-load x (explicit), gate, store =================
    {
        const int c = tid & 127;
#pragma unroll
        for (int w = 0; w < NW; ++w) {
            const float4 g = s_g4[w * 128 + c];
#pragma unroll
            for (int i = 0; i < 8; ++i) {
                const float4 v = xw[w * 2048 + i * TPB + tid];
                float4 o;
                o.x = v.x * g.x; o.y = v.y * g.y; o.z = v.z * g.z; o.w = v.w * g.w;
                yw[w * 2048 + i * TPB + tid] = o;
            }
        }
    }
}

extern "C" void kernel_launch(void* const* d_in, const int* in_sizes, int n_in,
                              void* d_out, int out_size, void* d_ws, size_t ws_size,
                              hipStream_t stream) {
    const float* x  = (const float*)d_in[0];
    const float* W1 = (const float*)d_in[1];
    const float* b1 = (const float*)d_in[2];
    const float* W2 = (const float*)d_in[3];
    const float* b2 = (const float*)d_in[4];
    float* y = (float*)d_out;

    const int n_windows = in_sizes[0] / (WIN * D);   // B * (M/WIN) = 4096
    const int n_blocks  = n_windows / NW;            // 2048
    se_block_kernel<<<dim3(n_blocks), dim3(TPB), 0, stream>>>(x, W1, b1, W2, b2, y);
}